// Round 9
// baseline (134.718 us; speedup 1.0000x reference)
//
#include <hip/hip_runtime.h>

// Problem sizes (fixed by the reference)
constexpr int kB    = 2048;  // batch
constexpr int kVIS  = 2048;  // visible units (GEMM K)
constexpr int kHID  = 1024;  // hidden units (GEMM N)
constexpr int kCLS  = 64;    // classes
constexpr float kLog2e = 1.4426950408889634f;

typedef __attribute__((ext_vector_type(8))) short bf16x8;
typedef __attribute__((ext_vector_type(4))) float f32x4;
typedef __attribute__((ext_vector_type(2))) float f32x2;

typedef __attribute__((address_space(3))) unsigned       as3_u32;
typedef __attribute__((address_space(1))) const unsigned as1_u32;

__device__ __forceinline__ void g2lds16(const void* g, void* l) {
    // async global->LDS DMA, 16 B per lane; LDS dest is wave-base + lane*16
    __builtin_amdgcn_global_load_lds((as1_u32*)g, (as3_u32*)l, 16, 0, 0);
}

__device__ __forceinline__ unsigned short f2bf(float x) {
    unsigned u = __float_as_uint(x);
    u += 0x7fffu + ((u >> 16) & 1u);
    return (unsigned short)(u >> 16);
}
__device__ __forceinline__ float bf2f(unsigned short h) {
    return __uint_as_float(((unsigned)h) << 16);
}

// ---------------- Prep (merged): split v, split+transpose W, pack+scale U ----------------
// blocks [0,4096): split_v ; [4096,6144): split_w_t ; [6144,6400): pack_u
__global__ __launch_bounds__(256) void prep_all(const float* __restrict__ v,
                                                const float* __restrict__ W,
                                                const float* __restrict__ U,
                                                unsigned short* __restrict__ vh,
                                                unsigned short* __restrict__ vl,
                                                unsigned short* __restrict__ wth,
                                                unsigned short* __restrict__ wtl,
                                                float* __restrict__ Utp) {
    __shared__ float T[32][33];
    const int bx = blockIdx.x;
    if (bx < 4096) {
        const int i = (bx * 256 + threadIdx.x) * 4;
        const float4 xv = *(const float4*)(v + i);
        ushort4 h, l;
        h.x = f2bf(xv.x); l.x = f2bf(xv.x - bf2f(h.x));
        h.y = f2bf(xv.y); l.y = f2bf(xv.y - bf2f(h.y));
        h.z = f2bf(xv.z); l.z = f2bf(xv.z - bf2f(h.z));
        h.w = f2bf(xv.w); l.w = f2bf(xv.w - bf2f(h.w));
        *(ushort4*)(vh + i) = h;
        *(ushort4*)(vl + i) = l;
    } else if (bx < 6144) {
        const int b = bx - 4096;
        const int n0 = (b & 31) * 32, k0 = (b >> 5) * 32;
        const int c = threadIdx.x & 31, r0 = threadIdx.x >> 5;
#pragma unroll
        for (int p = 0; p < 4; ++p) {
            const int r = r0 + p * 8;
            T[r][c] = W[(size_t)(k0 + r) * kHID + n0 + c];
        }
        __syncthreads();
#pragma unroll
        for (int p = 0; p < 4; ++p) {
            const int rr = r0 + p * 8;          // n offset
            const float x = T[c][rr];           // = W[k0+c][n0+rr]
            const unsigned short h = f2bf(x);
            const unsigned short l = f2bf(x - bf2f(h));
            const size_t o = (size_t)(n0 + rr) * kVIS + k0 + c;
            wth[o] = h;
            wtl[o] = l;
        }
    } else {
        const int id = (bx - 6144) * 256 + threadIdx.x;  // 0..65535
        const int j = id >> 6, y = id & 63;
        // packed: Utp[((j>>2)*64 + y)*4 + (j&3)]  ->  one dwordx4 per (j-quad, class)
        Utp[(((j >> 2) * kCLS + y) << 2) + (j & 3)] = U[(size_t)y * kHID + j] * kLog2e;
    }
}

// ---------------- Fused kernel: split-bf16 MFMA GEMM + softplus partial-F epilogue ------
// 64x64 tile, 4 waves remapped as (m-half, k-half) SPLIT-K: wave (mh,h) computes rows
// mh*32..+32 x ALL 64 cols for K-half h of each slab. This removes the B frag-read
// duplication: 12 b128 frag reads/wave/slab (A:4, B:8) vs 16 in the 2x2-quadrant map —
// frag volume was 2x staged volume, now 1.5x (the kernel is frag-read-bound: R8 showed
// dbuf/barrier changes are neutral, LDS pipe is the wall).
// K-half partials merge through the epilogue: psH[2][64][68] overlay (34.8 KB), h=0
// writes (acc+c)*log2e, h=1 writes acc*log2e; phase 2 sums both (broadcast reads, cheap).
// DMA dbuf (64 KiB exactly, 2 blocks/CU), XOR-swizzled octets, XCD swizzle: as R8.
__global__ __launch_bounds__(256) void gemm_fused(const unsigned short* __restrict__ vh,
                                                  const unsigned short* __restrict__ vl,
                                                  const unsigned short* __restrict__ wth,
                                                  const unsigned short* __restrict__ wtl,
                                                  const float* __restrict__ cvec,
                                                  const float* __restrict__ Utp,
                                                  float* __restrict__ Fpart) {
    __shared__ __align__(16) union SMem {
        unsigned short stage[2][4][64 * 64];  // [buf][Ah,Al,Bh,Bl][row][k]  = 65536 B
        float psH[2][64][68];                 // 34816 B, overlays stage
    } smem;

    const int tid = threadIdx.x;
    const int lane = tid & 63, wave = tid >> 6;
    const int mh = wave >> 1;                 // m-half: rows mh*32..+32
    const int kh = wave & 1;                  // k-half: k in [kh*32, kh*32+32) of each slab

    // XCD-aware decomposition of the 1D grid (512 blocks, 32 m-stripes x 16 n-tiles)
    const int bid = blockIdx.x;
    const int idx = bid >> 3;                           // 0..63
    const int mstripe = ((bid & 7) << 2) + (idx >> 4);  // 0..31
    const int ncol = idx & 15;                          // 0..15
    const int m0 = mstripe * 64, n0 = ncol * 64;

    // staging: thread covers rows r0 and r0+32; k-octet XOR-swizzled on global side
    const int r0 = tid >> 3, r1 = r0 + 32;
    const int oc = (((tid & 7) ^ ((tid >> 3) & 7)) << 3);   // global k-octet offset (elems)
    const size_t ga0 = (size_t)(m0 + r0) * kVIS + oc;
    const size_t ga1 = (size_t)(m0 + r1) * kVIS + oc;
    const size_t gb0 = (size_t)(n0 + r0) * kVIS + oc;
    const size_t gb1 = (size_t)(n0 + r1) * kVIS + oc;
    const int l0 = (r0 << 6) + ((tid & 7) << 3);            // physical LDS slot (elems)
    const int l1 = (r1 << 6) + ((tid & 7) << 3);

    // fragment addressing: frag[row][k], row-major LDK=64, swizzled octet.
    // A rows: mh*32 + {0,16} + fm ; B rows (out cols): {0,16,32,48} + fm — all preserve
    // row&7 == fm&7, so one xor key rx works for every tile.
    const int fm = lane & 15, fq = lane >> 4;
    const int rx = fm & 7;
    const int ar0 = (mh * 32 + fm) << 6, ar1 = (mh * 32 + 16 + fm) << 6;
    const int br0 = (fm) << 6,      br1 = (16 + fm) << 6;
    const int br2 = (32 + fm) << 6, br3 = (48 + fm) << 6;
    const int p = (((kh << 2) + fq) ^ rx) << 3;             // swizzled octet for this wave

    f32x4 acc[2][4] = {};   // [m-tile][n-tile], 32 VGPRs

    // prime: DMA slab 0 into buffer 0
    {
        unsigned short* Ah = smem.stage[0][0];
        unsigned short* Al = smem.stage[0][1];
        unsigned short* Bh = smem.stage[0][2];
        unsigned short* Bl = smem.stage[0][3];
        g2lds16(vh + ga0, Ah + l0);  g2lds16(vh + ga1, Ah + l1);
        g2lds16(vl + ga0, Al + l0);  g2lds16(vl + ga1, Al + l1);
        g2lds16(wth + gb0, Bh + l0); g2lds16(wth + gb1, Bh + l1);
        g2lds16(wtl + gb0, Bl + l0); g2lds16(wtl + gb1, Bl + l1);
    }
    __syncthreads();  // drain prime DMA

    int cur = 0;
    for (int k0 = 0; k0 < kVIS; k0 += 64) {
        // prefetch next slab into the idle buffer (flies during this slab's compute)
        if (k0 + 64 < kVIS) {
            unsigned short* Ah = smem.stage[cur ^ 1][0];
            unsigned short* Al = smem.stage[cur ^ 1][1];
            unsigned short* Bh = smem.stage[cur ^ 1][2];
            unsigned short* Bl = smem.stage[cur ^ 1][3];
            const int ko = k0 + 64;
            g2lds16(vh + ga0 + ko, Ah + l0);  g2lds16(vh + ga1 + ko, Ah + l1);
            g2lds16(vl + ga0 + ko, Al + l0);  g2lds16(vl + ga1 + ko, Al + l1);
            g2lds16(wth + gb0 + ko, Bh + l0); g2lds16(wth + gb1 + ko, Bh + l1);
            g2lds16(wtl + gb0 + ko, Bl + l0); g2lds16(wtl + gb1 + ko, Bl + l1);
        }
        const unsigned short* Ah = smem.stage[cur][0];
        const unsigned short* Al = smem.stage[cur][1];
        const unsigned short* Bh = smem.stage[cur][2];
        const unsigned short* Bl = smem.stage[cur][3];
        // 12 frag reads (A:4, B:8) for this wave's K=32 half
        const bf16x8 a_h0 = *(const bf16x8*)(Ah + ar0 + p);
        const bf16x8 a_h1 = *(const bf16x8*)(Ah + ar1 + p);
        const bf16x8 a_l0 = *(const bf16x8*)(Al + ar0 + p);
        const bf16x8 a_l1 = *(const bf16x8*)(Al + ar1 + p);
        const bf16x8 b_h0 = *(const bf16x8*)(Bh + br0 + p);
        const bf16x8 b_h1 = *(const bf16x8*)(Bh + br1 + p);
        const bf16x8 b_h2 = *(const bf16x8*)(Bh + br2 + p);
        const bf16x8 b_h3 = *(const bf16x8*)(Bh + br3 + p);
        const bf16x8 b_l0 = *(const bf16x8*)(Bl + br0 + p);
        const bf16x8 b_l1 = *(const bf16x8*)(Bl + br1 + p);
        const bf16x8 b_l2 = *(const bf16x8*)(Bl + br2 + p);
        const bf16x8 b_l3 = *(const bf16x8*)(Bl + br3 + p);
        // 24 MFMA: 2 m-tiles x 4 n-tiles x {hh, hl, lh}
        acc[0][0] = __builtin_amdgcn_mfma_f32_16x16x32_bf16(a_h0, b_h0, acc[0][0], 0, 0, 0);
        acc[0][0] = __builtin_amdgcn_mfma_f32_16x16x32_bf16(a_h0, b_l0, acc[0][0], 0, 0, 0);
        acc[0][0] = __builtin_amdgcn_mfma_f32_16x16x32_bf16(a_l0, b_h0, acc[0][0], 0, 0, 0);
        acc[0][1] = __builtin_amdgcn_mfma_f32_16x16x32_bf16(a_h0, b_h1, acc[0][1], 0, 0, 0);
        acc[0][1] = __builtin_amdgcn_mfma_f32_16x16x32_bf16(a_h0, b_l1, acc[0][1], 0, 0, 0);
        acc[0][1] = __builtin_amdgcn_mfma_f32_16x16x32_bf16(a_l0, b_h1, acc[0][1], 0, 0, 0);
        acc[0][2] = __builtin_amdgcn_mfma_f32_16x16x32_bf16(a_h0, b_h2, acc[0][2], 0, 0, 0);
        acc[0][2] = __builtin_amdgcn_mfma_f32_16x16x32_bf16(a_h0, b_l2, acc[0][2], 0, 0, 0);
        acc[0][2] = __builtin_amdgcn_mfma_f32_16x16x32_bf16(a_l0, b_h2, acc[0][2], 0, 0, 0);
        acc[0][3] = __builtin_amdgcn_mfma_f32_16x16x32_bf16(a_h0, b_h3, acc[0][3], 0, 0, 0);
        acc[0][3] = __builtin_amdgcn_mfma_f32_16x16x32_bf16(a_h0, b_l3, acc[0][3], 0, 0, 0);
        acc[0][3] = __builtin_amdgcn_mfma_f32_16x16x32_bf16(a_l0, b_h3, acc[0][3], 0, 0, 0);
        acc[1][0] = __builtin_amdgcn_mfma_f32_16x16x32_bf16(a_h1, b_h0, acc[1][0], 0, 0, 0);
        acc[1][0] = __builtin_amdgcn_mfma_f32_16x16x32_bf16(a_h1, b_l0, acc[1][0], 0, 0, 0);
        acc[1][0] = __builtin_amdgcn_mfma_f32_16x16x32_bf16(a_l1, b_h0, acc[1][0], 0, 0, 0);
        acc[1][1] = __builtin_amdgcn_mfma_f32_16x16x32_bf16(a_h1, b_h1, acc[1][1], 0, 0, 0);
        acc[1][1] = __builtin_amdgcn_mfma_f32_16x16x32_bf16(a_h1, b_l1, acc[1][1], 0, 0, 0);
        acc[1][1] = __builtin_amdgcn_mfma_f32_16x16x32_bf16(a_l1, b_h1, acc[1][1], 0, 0, 0);
        acc[1][2] = __builtin_amdgcn_mfma_f32_16x16x32_bf16(a_h1, b_h2, acc[1][2], 0, 0, 0);
        acc[1][2] = __builtin_amdgcn_mfma_f32_16x16x32_bf16(a_h1, b_l2, acc[1][2], 0, 0, 0);
        acc[1][2] = __builtin_amdgcn_mfma_f32_16x16x32_bf16(a_l1, b_h2, acc[1][2], 0, 0, 0);
        acc[1][3] = __builtin_amdgcn_mfma_f32_16x16x32_bf16(a_h1, b_h3, acc[1][3], 0, 0, 0);
        acc[1][3] = __builtin_amdgcn_mfma_f32_16x16x32_bf16(a_h1, b_l3, acc[1][3], 0, 0, 0);
        acc[1][3] = __builtin_amdgcn_mfma_f32_16x16x32_bf16(a_l1, b_h3, acc[1][3], 0, 0, 0);
        // single barrier per slab: waves done reading cur; prefetch DMA drained
        __syncthreads();
        cur ^= 1;
    }

    // ---- epilogue phase 1: k-half partials -> psH[kh] (log2 domain; c added once, kh=0)
    // write pattern: lanes (fm,fq) -> addr (fq*4+r)*68 + j*16+fm => 2-way bank (free)
#pragma unroll
    for (int j = 0; j < 4; ++j) {
        const int col = j * 16 + fm;                   // local hid col 0..63
        const float cadd = kh ? 0.f : cvec[n0 + col];
#pragma unroll
        for (int i = 0; i < 2; ++i) {
            const int rbase = mh * 32 + i * 16 + fq * 4;  // local row
#pragma unroll
            for (int r = 0; r < 4; ++r)
                smem.psH[kh][rbase + r][col] = (acc[i][j][r] + cadd) * kLog2e;
        }
    }
    __syncthreads();

    // ---- epilogue phase 2: packed-f32 softplus; wave owns rows [wave*16,+16), lane=class
    const int q0 = (n0 >> 2);
    f32x2 relu2[16], prod2[16];
#pragma unroll
    for (int rr = 0; rr < 16; ++rr) { relu2[rr] = (f32x2)(0.f); prod2[rr] = (f32x2)(1.f); }

    const f32x2 zero2 = (f32x2)(0.f);
    for (int jc = 0; jc < 64; jc += 8) {
        const float4 ua = ((const float4*)Utp)[(q0 + (jc >> 2) + 0) * kCLS + lane];
        const float4 ub = ((const float4*)Utp)[(q0 + (jc >> 2) + 1) * kCLS + lane];
        const f32x2 u01 = {ua.x, ua.y}, u23 = {ua.z, ua.w};
        const f32x2 u45 = {ub.x, ub.y}, u67 = {ub.z, ub.w};
#pragma unroll
        for (int rr = 0; rr < 16; ++rr) {
            const int row = wave * 16 + rr;
            const float4 pa0 = *(const float4*)&smem.psH[0][row][jc];      // broadcast
            const float4 pa1 = *(const float4*)&smem.psH[0][row][jc + 4];  // broadcast
            const float4 pb0 = *(const float4*)&smem.psH[1][row][jc];      // broadcast
            const float4 pb1 = *(const float4*)&smem.psH[1][row][jc + 4];  // broadcast
            f32x2 tp[4];
            tp[0] = (f32x2){pa0.x + pb0.x, pa0.y + pb0.y} + u01;
            tp[1] = (f32x2){pa0.z + pb0.z, pa0.w + pb0.w} + u23;
            tp[2] = (f32x2){pa1.x + pb1.x, pa1.y + pb1.y} + u45;
            tp[3] = (f32x2){pa1.z + pb1.z, pa1.w + pb1.w} + u67;
#pragma unroll
            for (int g = 0; g < 4; ++g) {
                const f32x2 t = tp[g];
                f32x2 e;
                e.x = __builtin_amdgcn_exp2f(-__builtin_fabsf(t.x));
                e.y = __builtin_amdgcn_exp2f(-__builtin_fabsf(t.y));
                prod2[rr] = __builtin_elementwise_fma(prod2[rr], e, prod2[rr]);  // *= (1+e), <=2^32/comp
                relu2[rr] += __builtin_elementwise_max(t, zero2);
            }
        }
    }
#pragma unroll
    for (int rr = 0; rr < 16; ++rr) {
        const float contrib = relu2[rr].x + relu2[rr].y +
                              __builtin_amdgcn_logf(prod2[rr].x * prod2[rr].y);  // log2 domain
        Fpart[((size_t)ncol * kB + m0 + wave * 16 + rr) * kCLS + lane] = contrib;
    }
}

// ---------------- Final: sum 16 partials (double), softmax, argmax, one-hot ------------
__global__ __launch_bounds__(256) void softmax_final(const float* __restrict__ Fpart,
                                                     const float* __restrict__ dvec,
                                                     float* __restrict__ out) {
    const int tid = threadIdx.x;
    const int lane = tid & 63, wave = tid >> 6;
    const int row = blockIdx.x * 4 + wave;
    double s = 0.0;
#pragma unroll
    for (int k = 0; k < kHID / 64; ++k)
        s += (double)Fpart[((size_t)k * kB + row) * kCLS + lane];
    const float G = (float)s + dvec[lane] * kLog2e;  // log2-domain logit

    float m = G;
    int mi = lane;
#pragma unroll
    for (int off = 32; off; off >>= 1) {
        const float om = __shfl_xor(m, off);
        const int   oi = __shfl_xor(mi, off);
        if (om > m || (om == m && oi < mi)) { m = om; mi = oi; }  // first-index tie-break
    }
    const float e2 = __builtin_amdgcn_exp2f(G - m);
    float ssum = e2;
#pragma unroll
    for (int off = 32; off; off >>= 1) ssum += __shfl_xor(ssum, off);
    out[(size_t)row * kCLS + lane] = e2 / ssum;
    out[(size_t)kB * kCLS + (size_t)row * kCLS + lane] = (lane == mi) ? 1.0f : 0.0f;
}

// ================= Fallback (round-1, known-passing) if ws is too small =================
constexpr int BM = 64, BN = 64, BK = 16;

__global__ __launch_bounds__(256) void gemm_vw(const float* __restrict__ V,
                                               const float* __restrict__ Wm,
                                               const float* __restrict__ cvec,
                                               float* __restrict__ pre) {
    __shared__ float As[BK][BM + 4];
    __shared__ float Bs[BK][BN + 4];
    const int tid = threadIdx.x;
    const int tx = tid & 15, ty = tid >> 4;
    const int m0 = blockIdx.y * BM, n0 = blockIdx.x * BN;
    const int arow = tid >> 2, acol = (tid & 3) << 2;
    const int brow = tid >> 4, bcol = (tid & 15) << 2;
    const float* vptr = V + (size_t)(m0 + arow) * kVIS + acol;
    const float* wptr = Wm + (size_t)brow * kHID + n0 + bcol;
    float acc[4][4] = {};
    for (int k0 = 0; k0 < kVIS; k0 += BK) {
        const float4 a4 = *(const float4*)(vptr + k0);
        const float4 b4 = *(const float4*)(wptr + (size_t)k0 * kHID);
        __syncthreads();
        As[acol + 0][arow] = a4.x; As[acol + 1][arow] = a4.y;
        As[acol + 2][arow] = a4.z; As[acol + 3][arow] = a4.w;
        *(float4*)&Bs[brow][bcol] = b4;
        __syncthreads();
#pragma unroll
        for (int k = 0; k < BK; ++k) {
            const float4 av = *(const float4*)&As[k][ty << 2];
            const float4 bv = *(const float4*)&Bs[k][tx << 2];
            const float a[4] = {av.x, av.y, av.z, av.w};
            const float b[4] = {bv.x, bv.y, bv.z, bv.w};
#pragma unroll
            for (int i = 0; i < 4; ++i)
#pragma unroll
                for (int j = 0; j < 4; ++j) acc[i][j] += a[i] * b[j];
        }
    }
#pragma unroll
    for (int i = 0; i < 4; ++i) {
        const int row = m0 + (ty << 2) + i;
        const int col = n0 + (tx << 2);
        const float4 cv = *(const float4*)(cvec + col);
        float4 o;
        o.x = acc[i][0] + cv.x; o.y = acc[i][1] + cv.y;
        o.z = acc[i][2] + cv.z; o.w = acc[i][3] + cv.w;
        *(float4*)(pre + (size_t)row * kHID + col) = o;
    }
}

__device__ __forceinline__ float softplus_f(float x) {
    return fmaxf(x, 0.f) + __logf(1.f + __expf(-fabsf(x)));
}

__global__ __launch_bounds__(256) void classify(const float* __restrict__ pre,
                                                const float* __restrict__ U,
                                                const float* __restrict__ dvec,
                                                float* __restrict__ out) {
    __shared__ float preS[4][kHID];
    __shared__ float Fs[4][kCLS];
    const int tid = threadIdx.x;
    const int lane = tid & 63, wave = tid >> 6;
    const int b0 = blockIdx.x * 4;
    const float4* src = (const float4*)(pre + (size_t)b0 * kHID);
    float4* dst = (float4*)preS;
    for (int i = tid; i < kHID; i += 256) dst[i] = src[i];
    __syncthreads();
    for (int yi = 0; yi < 16; ++yi) {
        const int y = (wave << 4) + yi;
        const float* Uy = U + (size_t)y * kHID;
        float a0 = 0.f, a1 = 0.f, a2 = 0.f, a3 = 0.f;
#pragma unroll
        for (int it = 0; it < kHID / 64; ++it) {
            const int j = lane + (it << 6);
            const float u = Uy[j];
            a0 += softplus_f(preS[0][j] + u);
            a1 += softplus_f(preS[1][j] + u);
            a2 += softplus_f(preS[2][j] + u);
            a3 += softplus_f(preS[3][j] + u);
        }
        double d0 = a0, d1 = a1, d2 = a2, d3 = a3;
#pragma unroll
        for (int off = 32; off; off >>= 1) {
            d0 += __shfl_xor(d0, off); d1 += __shfl_xor(d1, off);
            d2 += __shfl_xor(d2, off); d3 += __shfl_xor(d3, off);
        }
        if (lane == 0) {
            const float dy = dvec[y];
            Fs[0][y] = (float)d0 + dy; Fs[1][y] = (float)d1 + dy;
            Fs[2][y] = (float)d2 + dy; Fs[3][y] = (float)d3 + dy;
        }
    }
    __syncthreads();
    const float F = Fs[wave][lane];
    float m = F; int mi = lane;
#pragma unroll
    for (int off = 32; off; off >>= 1) {
        const float om = __shfl_xor(m, off);
        const int oi = __shfl_xor(mi, off);
        if (om > m || (om == m && oi < mi)) { m = om; mi = oi; }
    }
    const float e = __expf(F - m);
    float s = e;
#pragma unroll
    for (int off = 32; off; off >>= 1) s += __shfl_xor(s, off);
    const int row = b0 + wave;
    out[(size_t)row * kCLS + lane] = e / s;
    out[(size_t)kB * kCLS + (size_t)row * kCLS + lane] = (lane == mi) ? 1.0f : 0.0f;
}

extern "C" void kernel_launch(void* const* d_in, const int* in_sizes, int n_in,
                              void* d_out, int out_size, void* d_ws, size_t ws_size,
                              hipStream_t stream) {
    const float* v = (const float*)d_in[0];
    const float* W = (const float*)d_in[1];
    const float* c = (const float*)d_in[2];
    const float* d = (const float*)d_in[3];
    const float* U = (const float*)d_in[4];
    float* out = (float*)d_out;
    char* ws = (char*)d_ws;

    // ws layout: vh 8MB | vl 8MB | Wt_h 4MB | Wt_l 4MB | Utp 256KB | Fpart 8MB
    const size_t need = 33816576;
    if (ws_size >= need) {
        unsigned short* vh  = (unsigned short*)(ws);
        unsigned short* vl  = (unsigned short*)(ws + 8388608);
        unsigned short* wth = (unsigned short*)(ws + 16777216);
        unsigned short* wtl = (unsigned short*)(ws + 20971520);
        float* Utp   = (float*)(ws + 25165824);
        float* Fpart = (float*)(ws + 25427968);
        prep_all<<<6400, 256, 0, stream>>>(v, W, U, vh, vl, wth, wtl, Utp);
        gemm_fused<<<512, 256, 0, stream>>>(vh, vl, wth, wtl, c, Utp, Fpart);
        softmax_final<<<kB / 4, 256, 0, stream>>>(Fpart, d, out);
    } else {
        float* pre = (float*)ws;
        gemm_vw<<<dim3(kHID / BN, kB / BM), 256, 0, stream>>>(v, W, c, pre);
        classify<<<kB / 4, 256, 0, stream>>>(pre, U, d, out);
    }
}

// Round 10
// 130.688 us; speedup vs baseline: 1.0308x; 1.0308x over previous
//
#include <hip/hip_runtime.h>

// Problem sizes (fixed by the reference)
constexpr int kB    = 2048;  // batch
constexpr int kVIS  = 2048;  // visible units (GEMM K)
constexpr int kHID  = 1024;  // hidden units (GEMM N)
constexpr int kCLS  = 64;    // classes
constexpr float kLog2e = 1.4426950408889634f;

typedef __attribute__((ext_vector_type(8))) short bf16x8;
typedef __attribute__((ext_vector_type(4))) float f32x4;
typedef __attribute__((ext_vector_type(2))) float f32x2;

typedef __attribute__((address_space(3))) unsigned       as3_u32;
typedef __attribute__((address_space(1))) const unsigned as1_u32;

__device__ __forceinline__ void g2lds16(const void* g, void* l) {
    // async global->LDS DMA, 16 B per lane; LDS dest is wave-base + lane*16
    __builtin_amdgcn_global_load_lds((as1_u32*)g, (as3_u32*)l, 16, 0, 0);
}

__device__ __forceinline__ unsigned short f2bf(float x) {
    unsigned u = __float_as_uint(x);
    u += 0x7fffu + ((u >> 16) & 1u);
    return (unsigned short)(u >> 16);
}
__device__ __forceinline__ float bf2f(unsigned short h) {
    return __uint_as_float(((unsigned)h) << 16);
}

// ---------------- Prep (merged): split v, split+transpose W, pack+scale U ----------------
// blocks [0,4096): split_v ; [4096,6144): split_w_t ; [6144,6400): pack_u
__global__ __launch_bounds__(256) void prep_all(const float* __restrict__ v,
                                                const float* __restrict__ W,
                                                const float* __restrict__ U,
                                                unsigned short* __restrict__ vh,
                                                unsigned short* __restrict__ vl,
                                                unsigned short* __restrict__ wth,
                                                unsigned short* __restrict__ wtl,
                                                float* __restrict__ Utp) {
    __shared__ float T[32][33];
    const int bx = blockIdx.x;
    if (bx < 4096) {
        const int i = (bx * 256 + threadIdx.x) * 4;
        const float4 xv = *(const float4*)(v + i);
        ushort4 h, l;
        h.x = f2bf(xv.x); l.x = f2bf(xv.x - bf2f(h.x));
        h.y = f2bf(xv.y); l.y = f2bf(xv.y - bf2f(h.y));
        h.z = f2bf(xv.z); l.z = f2bf(xv.z - bf2f(h.z));
        h.w = f2bf(xv.w); l.w = f2bf(xv.w - bf2f(h.w));
        *(ushort4*)(vh + i) = h;
        *(ushort4*)(vl + i) = l;
    } else if (bx < 6144) {
        const int b = bx - 4096;
        const int n0 = (b & 31) * 32, k0 = (b >> 5) * 32;
        const int c = threadIdx.x & 31, r0 = threadIdx.x >> 5;
#pragma unroll
        for (int p = 0; p < 4; ++p) {
            const int r = r0 + p * 8;
            T[r][c] = W[(size_t)(k0 + r) * kHID + n0 + c];
        }
        __syncthreads();
#pragma unroll
        for (int p = 0; p < 4; ++p) {
            const int rr = r0 + p * 8;          // n offset
            const float x = T[c][rr];           // = W[k0+c][n0+rr]
            const unsigned short h = f2bf(x);
            const unsigned short l = f2bf(x - bf2f(h));
            const size_t o = (size_t)(n0 + rr) * kVIS + k0 + c;
            wth[o] = h;
            wtl[o] = l;
        }
    } else {
        const int id = (bx - 6144) * 256 + threadIdx.x;  // 0..65535
        const int j = id >> 6, y = id & 63;
        // packed: Utp[((j>>2)*64 + y)*4 + (j&3)]  ->  one dwordx4 per (j-quad, class)
        Utp[(((j >> 2) * kCLS + y) << 2) + (j & 3)] = U[(size_t)y * kHID + j] * kLog2e;
    }
}

// ---------------- Fused kernel: split-bf16 MFMA GEMM + softplus partial-F epilogue ------
// 512 THREADS (8 waves), 64x64 tile, 3-way wave split (mh x nh x kh): wave (mh,nh,kh)
// computes output quadrant rows mh*32..+32 x cols nh*32..+32 for K-half kh of each slab.
// Rationale: since R4, occupancy has been grid-capped at 2 blocks x 4 waves = 8 waves/CU
// (18%) -- every LDS/barrier/frag tweak (R8 dbuf, R9 split-K) was neutral because the
// kernel is latency-starved, not pipe-starved. Same per-CU work, 2x resident waves.
// Per wave per slab: 8 b128 frag reads + 12 MFMA; acc = 2x2 f32x4 (16 VGPR) so 16
// waves/CU fits the <=128 VGPR budget. K-half partials merge via psH[2] overlay (R9).
// DMA dbuf 64 KiB exactly (2 blocks/CU), single barrier/slab, XOR octet swizzle,
// XCD swizzle, packed-f32 softplus epilogue: all unchanged from R8/R9.
__global__ __launch_bounds__(512, 4) void gemm_fused(const unsigned short* __restrict__ vh,
                                                     const unsigned short* __restrict__ vl,
                                                     const unsigned short* __restrict__ wth,
                                                     const unsigned short* __restrict__ wtl,
                                                     const float* __restrict__ cvec,
                                                     const float* __restrict__ Utp,
                                                     float* __restrict__ Fpart) {
    __shared__ __align__(16) union SMem {
        unsigned short stage[2][4][64 * 64];  // [buf][Ah,Al,Bh,Bl][row][k]  = 65536 B
        float psH[2][64][68];                 // 34816 B, overlays stage
    } smem;

    const int tid = threadIdx.x;
    const int lane = tid & 63, wave = tid >> 6;   // wave 0..7
    const int mh = wave >> 2;                     // m-half: rows mh*32..+32
    const int nh = (wave >> 1) & 1;               // n-half: cols nh*32..+32
    const int kh = wave & 1;                      // k-half: k in [kh*32,+32) of each slab

    // XCD-aware decomposition of the 1D grid (512 blocks, 32 m-stripes x 16 n-tiles)
    const int bid = blockIdx.x;
    const int idx = bid >> 3;                           // 0..63
    const int mstripe = ((bid & 7) << 2) + (idx >> 4);  // 0..31
    const int ncol = idx & 15;                          // 0..15
    const int m0 = mstripe * 64, n0 = ncol * 64;

    // staging: 512 threads x 16 B = one 8 KB array per DMA set; thread covers one row-slot
    const int r = tid >> 3;                                 // 0..63
    const int oc = (((tid & 7) ^ ((tid >> 3) & 7)) << 3);   // global k-octet (XOR swizzle)
    const size_t ga = (size_t)(m0 + r) * kVIS + oc;
    const size_t gb = (size_t)(n0 + r) * kVIS + oc;
    const int ls = (r << 6) + ((tid & 7) << 3);             // physical LDS slot (elems)

    // fragment addressing: frag[row][k], row-major LDK=64, swizzled octet.
    // All frag rows preserve row&7 == fm&7 (offsets 16/32/48 are multiples of 8).
    const int fm = lane & 15, fq = lane >> 4;
    const int rx = fm & 7;
    const int ar0 = (mh * 32 + fm) << 6, ar1 = (mh * 32 + 16 + fm) << 6;
    const int br0 = (nh * 32 + fm) << 6, br1 = (nh * 32 + 16 + fm) << 6;
    const int p = (((kh << 2) + fq) ^ rx) << 3;             // swizzled octet for this wave

    f32x4 acc[2][2] = {};   // [m-tile][n-tile], 16 VGPRs

    // prime: DMA slab 0 into buffer 0
    {
        g2lds16(vh + ga,  smem.stage[0][0] + ls);
        g2lds16(vl + ga,  smem.stage[0][1] + ls);
        g2lds16(wth + gb, smem.stage[0][2] + ls);
        g2lds16(wtl + gb, smem.stage[0][3] + ls);
    }
    __syncthreads();  // drain prime DMA

    int cur = 0;
    for (int k0 = 0; k0 < kVIS; k0 += 64) {
        // prefetch next slab into the idle buffer (flies during this slab's compute)
        if (k0 + 64 < kVIS) {
            const int ko = k0 + 64;
            g2lds16(vh + ga + ko,  smem.stage[cur ^ 1][0] + ls);
            g2lds16(vl + ga + ko,  smem.stage[cur ^ 1][1] + ls);
            g2lds16(wth + gb + ko, smem.stage[cur ^ 1][2] + ls);
            g2lds16(wtl + gb + ko, smem.stage[cur ^ 1][3] + ls);
        }
        const unsigned short* Ah = smem.stage[cur][0];
        const unsigned short* Al = smem.stage[cur][1];
        const unsigned short* Bh = smem.stage[cur][2];
        const unsigned short* Bl = smem.stage[cur][3];
        // 8 frag reads (A:4, B:4) for this wave's 32x32 quadrant, K=32 half
        const bf16x8 a_h0 = *(const bf16x8*)(Ah + ar0 + p);
        const bf16x8 a_h1 = *(const bf16x8*)(Ah + ar1 + p);
        const bf16x8 a_l0 = *(const bf16x8*)(Al + ar0 + p);
        const bf16x8 a_l1 = *(const bf16x8*)(Al + ar1 + p);
        const bf16x8 b_h0 = *(const bf16x8*)(Bh + br0 + p);
        const bf16x8 b_h1 = *(const bf16x8*)(Bh + br1 + p);
        const bf16x8 b_l0 = *(const bf16x8*)(Bl + br0 + p);
        const bf16x8 b_l1 = *(const bf16x8*)(Bl + br1 + p);
        // 12 MFMA: 2 m-tiles x 2 n-tiles x {hh, hl, lh}
        acc[0][0] = __builtin_amdgcn_mfma_f32_16x16x32_bf16(a_h0, b_h0, acc[0][0], 0, 0, 0);
        acc[0][0] = __builtin_amdgcn_mfma_f32_16x16x32_bf16(a_h0, b_l0, acc[0][0], 0, 0, 0);
        acc[0][0] = __builtin_amdgcn_mfma_f32_16x16x32_bf16(a_l0, b_h0, acc[0][0], 0, 0, 0);
        acc[0][1] = __builtin_amdgcn_mfma_f32_16x16x32_bf16(a_h0, b_h1, acc[0][1], 0, 0, 0);
        acc[0][1] = __builtin_amdgcn_mfma_f32_16x16x32_bf16(a_h0, b_l1, acc[0][1], 0, 0, 0);
        acc[0][1] = __builtin_amdgcn_mfma_f32_16x16x32_bf16(a_l0, b_h1, acc[0][1], 0, 0, 0);
        acc[1][0] = __builtin_amdgcn_mfma_f32_16x16x32_bf16(a_h1, b_h0, acc[1][0], 0, 0, 0);
        acc[1][0] = __builtin_amdgcn_mfma_f32_16x16x32_bf16(a_h1, b_l0, acc[1][0], 0, 0, 0);
        acc[1][0] = __builtin_amdgcn_mfma_f32_16x16x32_bf16(a_l1, b_h0, acc[1][0], 0, 0, 0);
        acc[1][1] = __builtin_amdgcn_mfma_f32_16x16x32_bf16(a_h1, b_h1, acc[1][1], 0, 0, 0);
        acc[1][1] = __builtin_amdgcn_mfma_f32_16x16x32_bf16(a_h1, b_l1, acc[1][1], 0, 0, 0);
        acc[1][1] = __builtin_amdgcn_mfma_f32_16x16x32_bf16(a_l1, b_h1, acc[1][1], 0, 0, 0);
        // single barrier per slab: waves done reading cur; prefetch DMA drained
        __syncthreads();
        cur ^= 1;
    }

    // ---- epilogue phase 1: k-half partials -> psH[kh] (log2 domain; c added once, kh=0)
    // for fixed kh, the 4 (mh,nh) waves tile the full 64x64 -> no overlap
#pragma unroll
    for (int j = 0; j < 2; ++j) {
        const int col = nh * 32 + j * 16 + fm;         // local hid col 0..63
        const float cadd = kh ? 0.f : cvec[n0 + col];
#pragma unroll
        for (int i = 0; i < 2; ++i) {
            const int rbase = mh * 32 + i * 16 + fq * 4;  // local row
#pragma unroll
            for (int rr = 0; rr < 4; ++rr)
                smem.psH[kh][rbase + rr][col] = (acc[i][j][rr] + cadd) * kLog2e;
        }
    }
    __syncthreads();

    // ---- epilogue phase 2: packed-f32 softplus; wave owns rows [wave*8,+8), lane=class
    const int q0 = (n0 >> 2);
    f32x2 relu2[8], prod2[8];
#pragma unroll
    for (int rr = 0; rr < 8; ++rr) { relu2[rr] = (f32x2)(0.f); prod2[rr] = (f32x2)(1.f); }

    const f32x2 zero2 = (f32x2)(0.f);
    for (int jc = 0; jc < 64; jc += 8) {
        const float4 ua = ((const float4*)Utp)[(q0 + (jc >> 2) + 0) * kCLS + lane];
        const float4 ub = ((const float4*)Utp)[(q0 + (jc >> 2) + 1) * kCLS + lane];
        const f32x2 u01 = {ua.x, ua.y}, u23 = {ua.z, ua.w};
        const f32x2 u45 = {ub.x, ub.y}, u67 = {ub.z, ub.w};
#pragma unroll
        for (int rr = 0; rr < 8; ++rr) {
            const int row = wave * 8 + rr;
            const float4 pa0 = *(const float4*)&smem.psH[0][row][jc];      // broadcast
            const float4 pa1 = *(const float4*)&smem.psH[0][row][jc + 4];  // broadcast
            const float4 pb0 = *(const float4*)&smem.psH[1][row][jc];      // broadcast
            const float4 pb1 = *(const float4*)&smem.psH[1][row][jc + 4];  // broadcast
            f32x2 tp[4];
            tp[0] = (f32x2){pa0.x + pb0.x, pa0.y + pb0.y} + u01;
            tp[1] = (f32x2){pa0.z + pb0.z, pa0.w + pb0.w} + u23;
            tp[2] = (f32x2){pa1.x + pb1.x, pa1.y + pb1.y} + u45;
            tp[3] = (f32x2){pa1.z + pb1.z, pa1.w + pb1.w} + u67;
#pragma unroll
            for (int g = 0; g < 4; ++g) {
                const f32x2 t = tp[g];
                f32x2 e;
                e.x = __builtin_amdgcn_exp2f(-__builtin_fabsf(t.x));
                e.y = __builtin_amdgcn_exp2f(-__builtin_fabsf(t.y));
                prod2[rr] = __builtin_elementwise_fma(prod2[rr], e, prod2[rr]);  // *= (1+e), <=2^32/comp
                relu2[rr] += __builtin_elementwise_max(t, zero2);
            }
        }
    }
#pragma unroll
    for (int rr = 0; rr < 8; ++rr) {
        const float contrib = relu2[rr].x + relu2[rr].y +
                              __builtin_amdgcn_logf(prod2[rr].x * prod2[rr].y);  // log2 domain
        Fpart[((size_t)ncol * kB + m0 + wave * 8 + rr) * kCLS + lane] = contrib;
    }
}

// ---------------- Final: sum 16 partials (double), softmax, argmax, one-hot ------------
__global__ __launch_bounds__(256) void softmax_final(const float* __restrict__ Fpart,
                                                     const float* __restrict__ dvec,
                                                     float* __restrict__ out) {
    const int tid = threadIdx.x;
    const int lane = tid & 63, wave = tid >> 6;
    const int row = blockIdx.x * 4 + wave;
    double s = 0.0;
#pragma unroll
    for (int k = 0; k < kHID / 64; ++k)
        s += (double)Fpart[((size_t)k * kB + row) * kCLS + lane];
    const float G = (float)s + dvec[lane] * kLog2e;  // log2-domain logit

    float m = G;
    int mi = lane;
#pragma unroll
    for (int off = 32; off; off >>= 1) {
        const float om = __shfl_xor(m, off);
        const int   oi = __shfl_xor(mi, off);
        if (om > m || (om == m && oi < mi)) { m = om; mi = oi; }  // first-index tie-break
    }
    const float e2 = __builtin_amdgcn_exp2f(G - m);
    float ssum = e2;
#pragma unroll
    for (int off = 32; off; off >>= 1) ssum += __shfl_xor(ssum, off);
    out[(size_t)row * kCLS + lane] = e2 / ssum;
    out[(size_t)kB * kCLS + (size_t)row * kCLS + lane] = (lane == mi) ? 1.0f : 0.0f;
}

// ================= Fallback (round-1, known-passing) if ws is too small =================
constexpr int BM = 64, BN = 64, BK = 16;

__global__ __launch_bounds__(256) void gemm_vw(const float* __restrict__ V,
                                               const float* __restrict__ Wm,
                                               const float* __restrict__ cvec,
                                               float* __restrict__ pre) {
    __shared__ float As[BK][BM + 4];
    __shared__ float Bs[BK][BN + 4];
    const int tid = threadIdx.x;
    const int tx = tid & 15, ty = tid >> 4;
    const int m0 = blockIdx.y * BM, n0 = blockIdx.x * BN;
    const int arow = tid >> 2, acol = (tid & 3) << 2;
    const int brow = tid >> 4, bcol = (tid & 15) << 2;
    const float* vptr = V + (size_t)(m0 + arow) * kVIS + acol;
    const float* wptr = Wm + (size_t)brow * kHID + n0 + bcol;
    float acc[4][4] = {};
    for (int k0 = 0; k0 < kVIS; k0 += BK) {
        const float4 a4 = *(const float4*)(vptr + k0);
        const float4 b4 = *(const float4*)(wptr + (size_t)k0 * kHID);
        __syncthreads();
        As[acol + 0][arow] = a4.x; As[acol + 1][arow] = a4.y;
        As[acol + 2][arow] = a4.z; As[acol + 3][arow] = a4.w;
        *(float4*)&Bs[brow][bcol] = b4;
        __syncthreads();
#pragma unroll
        for (int k = 0; k < BK; ++k) {
            const float4 av = *(const float4*)&As[k][ty << 2];
            const float4 bv = *(const float4*)&Bs[k][tx << 2];
            const float a[4] = {av.x, av.y, av.z, av.w};
            const float b[4] = {bv.x, bv.y, bv.z, bv.w};
#pragma unroll
            for (int i = 0; i < 4; ++i)
#pragma unroll
                for (int j = 0; j < 4; ++j) acc[i][j] += a[i] * b[j];
        }
    }
#pragma unroll
    for (int i = 0; i < 4; ++i) {
        const int row = m0 + (ty << 2) + i;
        const int col = n0 + (tx << 2);
        const float4 cv = *(const float4*)(cvec + col);
        float4 o;
        o.x = acc[i][0] + cv.x; o.y = acc[i][1] + cv.y;
        o.z = acc[i][2] + cv.z; o.w = acc[i][3] + cv.w;
        *(float4*)(pre + (size_t)row * kHID + col) = o;
    }
}

__device__ __forceinline__ float softplus_f(float x) {
    return fmaxf(x, 0.f) + __logf(1.f + __expf(-fabsf(x)));
}

__global__ __launch_bounds__(256) void classify(const float* __restrict__ pre,
                                                const float* __restrict__ U,
                                                const float* __restrict__ dvec,
                                                float* __restrict__ out) {
    __shared__ float preS[4][kHID];
    __shared__ float Fs[4][kCLS];
    const int tid = threadIdx.x;
    const int lane = tid & 63, wave = tid >> 6;
    const int b0 = blockIdx.x * 4;
    const float4* src = (const float4*)(pre + (size_t)b0 * kHID);
    float4* dst = (float4*)preS;
    for (int i = tid; i < kHID; i += 256) dst[i] = src[i];
    __syncthreads();
    for (int yi = 0; yi < 16; ++yi) {
        const int y = (wave << 4) + yi;
        const float* Uy = U + (size_t)y * kHID;
        float a0 = 0.f, a1 = 0.f, a2 = 0.f, a3 = 0.f;
#pragma unroll
        for (int it = 0; it < kHID / 64; ++it) {
            const int j = lane + (it << 6);
            const float u = Uy[j];
            a0 += softplus_f(preS[0][j] + u);
            a1 += softplus_f(preS[1][j] + u);
            a2 += softplus_f(preS[2][j] + u);
            a3 += softplus_f(preS[3][j] + u);
        }
        double d0 = a0, d1 = a1, d2 = a2, d3 = a3;
#pragma unroll
        for (int off = 32; off; off >>= 1) {
            d0 += __shfl_xor(d0, off); d1 += __shfl_xor(d1, off);
            d2 += __shfl_xor(d2, off); d3 += __shfl_xor(d3, off);
        }
        if (lane == 0) {
            const float dy = dvec[y];
            Fs[0][y] = (float)d0 + dy; Fs[1][y] = (float)d1 + dy;
            Fs[2][y] = (float)d2 + dy; Fs[3][y] = (float)d3 + dy;
        }
    }
    __syncthreads();
    const float F = Fs[wave][lane];
    float m = F; int mi = lane;
#pragma unroll
    for (int off = 32; off; off >>= 1) {
        const float om = __shfl_xor(m, off);
        const int oi = __shfl_xor(mi, off);
        if (om > m || (om == m && oi < mi)) { m = om; mi = oi; }
    }
    const float e = __expf(F - m);
    float s = e;
#pragma unroll
    for (int off = 32; off; off >>= 1) s += __shfl_xor(s, off);
    const int row = b0 + wave;
    out[(size_t)row * kCLS + lane] = e / s;
    out[(size_t)kB * kCLS + (size_t)row * kCLS + lane] = (lane == mi) ? 1.0f : 0.0f;
}

extern "C" void kernel_launch(void* const* d_in, const int* in_sizes, int n_in,
                              void* d_out, int out_size, void* d_ws, size_t ws_size,
                              hipStream_t stream) {
    const float* v = (const float*)d_in[0];
    const float* W = (const float*)d_in[1];
    const float* c = (const float*)d_in[2];
    const float* d = (const float*)d_in[3];
    const float* U = (const float*)d_in[4];
    float* out = (float*)d_out;
    char* ws = (char*)d_ws;

    // ws layout: vh 8MB | vl 8MB | Wt_h 4MB | Wt_l 4MB | Utp 256KB | Fpart 8MB
    const size_t need = 33816576;
    if (ws_size >= need) {
        unsigned short* vh  = (unsigned short*)(ws);
        unsigned short* vl  = (unsigned short*)(ws + 8388608);
        unsigned short* wth = (unsigned short*)(ws + 16777216);
        unsigned short* wtl = (unsigned short*)(ws + 20971520);
        float* Utp   = (float*)(ws + 25165824);
        float* Fpart = (float*)(ws + 25427968);
        prep_all<<<6400, 256, 0, stream>>>(v, W, U, vh, vl, wth, wtl, Utp);
        gemm_fused<<<512, 512, 0, stream>>>(vh, vl, wth, wtl, c, Utp, Fpart);
        softmax_final<<<kB / 4, 256, 0, stream>>>(Fpart, d, out);
    } else {
        float* pre = (float*)ws;
        gemm_vw<<<dim3(kHID / BN, kB / BM), 256, 0, stream>>>(v, W, c, pre);
        classify<<<kB / 4, 256, 0, stream>>>(pre, U, d, out);
    }
}

// Round 11
// 128.433 us; speedup vs baseline: 1.0489x; 1.0176x over previous
//
#include <hip/hip_runtime.h>

// Problem sizes (fixed by the reference)
constexpr int kB    = 2048;  // batch
constexpr int kVIS  = 2048;  // visible units (GEMM K)
constexpr int kHID  = 1024;  // hidden units (GEMM N)
constexpr int kCLS  = 64;    // classes
constexpr float kLog2e = 1.4426950408889634f;

typedef __attribute__((ext_vector_type(8))) short bf16x8;
typedef __attribute__((ext_vector_type(4))) float f32x4;
typedef __attribute__((ext_vector_type(2))) float f32x2;

typedef __attribute__((address_space(3))) unsigned       as3_u32;
typedef __attribute__((address_space(1))) const unsigned as1_u32;

__device__ __forceinline__ void g2lds16(const void* g, void* l) {
    // async global->LDS DMA, 16 B per lane; LDS dest is wave-base + lane*16
    __builtin_amdgcn_global_load_lds((as1_u32*)g, (as3_u32*)l, 16, 0, 0);
}

__device__ __forceinline__ unsigned short f2bf(float x) {
    unsigned u = __float_as_uint(x);
    u += 0x7fffu + ((u >> 16) & 1u);
    return (unsigned short)(u >> 16);
}
__device__ __forceinline__ float bf2f(unsigned short h) {
    return __uint_as_float(((unsigned)h) << 16);
}

// ---------------- Prep (merged): split v, split+transpose W, pack+scale U ----------------
// blocks [0,4096): split_v ; [4096,6144): split_w_t ; [6144,6400): pack_u
__global__ __launch_bounds__(256) void prep_all(const float* __restrict__ v,
                                                const float* __restrict__ W,
                                                const float* __restrict__ U,
                                                unsigned short* __restrict__ vh,
                                                unsigned short* __restrict__ vl,
                                                unsigned short* __restrict__ wth,
                                                unsigned short* __restrict__ wtl,
                                                float* __restrict__ Utp) {
    __shared__ float T[32][33];
    const int bx = blockIdx.x;
    if (bx < 4096) {
        const int i = (bx * 256 + threadIdx.x) * 4;
        const float4 xv = *(const float4*)(v + i);
        ushort4 h, l;
        h.x = f2bf(xv.x); l.x = f2bf(xv.x - bf2f(h.x));
        h.y = f2bf(xv.y); l.y = f2bf(xv.y - bf2f(h.y));
        h.z = f2bf(xv.z); l.z = f2bf(xv.z - bf2f(h.z));
        h.w = f2bf(xv.w); l.w = f2bf(xv.w - bf2f(h.w));
        *(ushort4*)(vh + i) = h;
        *(ushort4*)(vl + i) = l;
    } else if (bx < 6144) {
        const int b = bx - 4096;
        const int n0 = (b & 31) * 32, k0 = (b >> 5) * 32;
        const int c = threadIdx.x & 31, r0 = threadIdx.x >> 5;
#pragma unroll
        for (int p = 0; p < 4; ++p) {
            const int r = r0 + p * 8;
            T[r][c] = W[(size_t)(k0 + r) * kHID + n0 + c];
        }
        __syncthreads();
#pragma unroll
        for (int p = 0; p < 4; ++p) {
            const int rr = r0 + p * 8;          // n offset
            const float x = T[c][rr];           // = W[k0+c][n0+rr]
            const unsigned short h = f2bf(x);
            const unsigned short l = f2bf(x - bf2f(h));
            const size_t o = (size_t)(n0 + rr) * kVIS + k0 + c;
            wth[o] = h;
            wtl[o] = l;
        }
    } else {
        const int id = (bx - 6144) * 256 + threadIdx.x;  // 0..65535
        const int j = id >> 6, y = id & 63;
        // packed: Utp[((j>>2)*64 + y)*4 + (j&3)]  ->  one dwordx4 per (j-quad, class)
        Utp[(((j >> 2) * kCLS + y) << 2) + (j & 3)] = U[(size_t)y * kHID + j] * kLog2e;
    }
}

// ---------------- Fused kernel: split-bf16 MFMA GEMM + softplus partial-F epilogue ------
// 512 threads (8 waves), 64x64 tile, 3-way wave split (mh x nh x kh) — R10 structure.
// NEW (R11): the epilogue was reading BOTH k-half planes per chunk (4 b128) — at 12 cyc
// per ds_read_b128 that was ~20 µs/CU of LDS pipe, as much as the whole GEMM's frag
// reads. A one-shot merge pass (psH[0] += psH[1], 2 float4/thread, ~0.5 µs) halves the
// epilogue read volume to its structural floor (each f32 read exactly once).
// DMA dbuf 64 KiB exactly (2 blocks/CU), single barrier/slab, XOR octet swizzle,
// XCD swizzle, packed-f32 softplus epilogue: unchanged.
__global__ __launch_bounds__(512, 4) void gemm_fused(const unsigned short* __restrict__ vh,
                                                     const unsigned short* __restrict__ vl,
                                                     const unsigned short* __restrict__ wth,
                                                     const unsigned short* __restrict__ wtl,
                                                     const float* __restrict__ cvec,
                                                     const float* __restrict__ Utp,
                                                     float* __restrict__ Fpart) {
    __shared__ __align__(16) union SMem {
        unsigned short stage[2][4][64 * 64];  // [buf][Ah,Al,Bh,Bl][row][k]  = 65536 B
        float psH[2][64][68];                 // 34816 B, overlays stage
    } smem;

    const int tid = threadIdx.x;
    const int lane = tid & 63, wave = tid >> 6;   // wave 0..7
    const int mh = wave >> 2;                     // m-half: rows mh*32..+32
    const int nh = (wave >> 1) & 1;               // n-half: cols nh*32..+32
    const int kh = wave & 1;                      // k-half: k in [kh*32,+32) of each slab

    // XCD-aware decomposition of the 1D grid (512 blocks, 32 m-stripes x 16 n-tiles)
    const int bid = blockIdx.x;
    const int idx = bid >> 3;                           // 0..63
    const int mstripe = ((bid & 7) << 2) + (idx >> 4);  // 0..31
    const int ncol = idx & 15;                          // 0..15
    const int m0 = mstripe * 64, n0 = ncol * 64;

    // staging: 512 threads x 16 B = one 8 KB array per DMA set; thread covers one row-slot
    const int r = tid >> 3;                                 // 0..63
    const int oc = (((tid & 7) ^ ((tid >> 3) & 7)) << 3);   // global k-octet (XOR swizzle)
    const size_t ga = (size_t)(m0 + r) * kVIS + oc;
    const size_t gb = (size_t)(n0 + r) * kVIS + oc;
    const int ls = (r << 6) + ((tid & 7) << 3);             // physical LDS slot (elems)

    // fragment addressing: frag[row][k], row-major LDK=64, swizzled octet.
    const int fm = lane & 15, fq = lane >> 4;
    const int rx = fm & 7;
    const int ar0 = (mh * 32 + fm) << 6, ar1 = (mh * 32 + 16 + fm) << 6;
    const int br0 = (nh * 32 + fm) << 6, br1 = (nh * 32 + 16 + fm) << 6;
    const int p = (((kh << 2) + fq) ^ rx) << 3;             // swizzled octet for this wave

    f32x4 acc[2][2] = {};   // [m-tile][n-tile], 16 VGPRs

    // prime: DMA slab 0 into buffer 0
    {
        g2lds16(vh + ga,  smem.stage[0][0] + ls);
        g2lds16(vl + ga,  smem.stage[0][1] + ls);
        g2lds16(wth + gb, smem.stage[0][2] + ls);
        g2lds16(wtl + gb, smem.stage[0][3] + ls);
    }
    __syncthreads();  // drain prime DMA

    int cur = 0;
    for (int k0 = 0; k0 < kVIS; k0 += 64) {
        // prefetch next slab into the idle buffer (flies during this slab's compute)
        if (k0 + 64 < kVIS) {
            const int ko = k0 + 64;
            g2lds16(vh + ga + ko,  smem.stage[cur ^ 1][0] + ls);
            g2lds16(vl + ga + ko,  smem.stage[cur ^ 1][1] + ls);
            g2lds16(wth + gb + ko, smem.stage[cur ^ 1][2] + ls);
            g2lds16(wtl + gb + ko, smem.stage[cur ^ 1][3] + ls);
        }
        const unsigned short* Ah = smem.stage[cur][0];
        const unsigned short* Al = smem.stage[cur][1];
        const unsigned short* Bh = smem.stage[cur][2];
        const unsigned short* Bl = smem.stage[cur][3];
        // 8 frag reads (A:4, B:4) for this wave's 32x32 quadrant, K=32 half
        const bf16x8 a_h0 = *(const bf16x8*)(Ah + ar0 + p);
        const bf16x8 a_h1 = *(const bf16x8*)(Ah + ar1 + p);
        const bf16x8 a_l0 = *(const bf16x8*)(Al + ar0 + p);
        const bf16x8 a_l1 = *(const bf16x8*)(Al + ar1 + p);
        const bf16x8 b_h0 = *(const bf16x8*)(Bh + br0 + p);
        const bf16x8 b_h1 = *(const bf16x8*)(Bh + br1 + p);
        const bf16x8 b_l0 = *(const bf16x8*)(Bl + br0 + p);
        const bf16x8 b_l1 = *(const bf16x8*)(Bl + br1 + p);
        // 12 MFMA: 2 m-tiles x 2 n-tiles x {hh, hl, lh}
        acc[0][0] = __builtin_amdgcn_mfma_f32_16x16x32_bf16(a_h0, b_h0, acc[0][0], 0, 0, 0);
        acc[0][0] = __builtin_amdgcn_mfma_f32_16x16x32_bf16(a_h0, b_l0, acc[0][0], 0, 0, 0);
        acc[0][0] = __builtin_amdgcn_mfma_f32_16x16x32_bf16(a_l0, b_h0, acc[0][0], 0, 0, 0);
        acc[0][1] = __builtin_amdgcn_mfma_f32_16x16x32_bf16(a_h0, b_h1, acc[0][1], 0, 0, 0);
        acc[0][1] = __builtin_amdgcn_mfma_f32_16x16x32_bf16(a_h0, b_l1, acc[0][1], 0, 0, 0);
        acc[0][1] = __builtin_amdgcn_mfma_f32_16x16x32_bf16(a_l0, b_h1, acc[0][1], 0, 0, 0);
        acc[1][0] = __builtin_amdgcn_mfma_f32_16x16x32_bf16(a_h1, b_h0, acc[1][0], 0, 0, 0);
        acc[1][0] = __builtin_amdgcn_mfma_f32_16x16x32_bf16(a_h1, b_l0, acc[1][0], 0, 0, 0);
        acc[1][0] = __builtin_amdgcn_mfma_f32_16x16x32_bf16(a_l1, b_h0, acc[1][0], 0, 0, 0);
        acc[1][1] = __builtin_amdgcn_mfma_f32_16x16x32_bf16(a_h1, b_h1, acc[1][1], 0, 0, 0);
        acc[1][1] = __builtin_amdgcn_mfma_f32_16x16x32_bf16(a_h1, b_l1, acc[1][1], 0, 0, 0);
        acc[1][1] = __builtin_amdgcn_mfma_f32_16x16x32_bf16(a_l1, b_h1, acc[1][1], 0, 0, 0);
        // single barrier per slab: waves done reading cur; prefetch DMA drained
        __syncthreads();
        cur ^= 1;
    }

    // ---- epilogue phase 1: k-half partials -> psH[kh] (log2 domain; c added once, kh=0)
    // for fixed kh, the 4 (mh,nh) waves tile the full 64x64 -> no overlap
#pragma unroll
    for (int j = 0; j < 2; ++j) {
        const int col = nh * 32 + j * 16 + fm;         // local hid col 0..63
        const float cadd = kh ? 0.f : cvec[n0 + col];
#pragma unroll
        for (int i = 0; i < 2; ++i) {
            const int rbase = mh * 32 + i * 16 + fq * 4;  // local row
#pragma unroll
            for (int rr = 0; rr < 4; ++rr)
                smem.psH[kh][rbase + rr][col] = (acc[i][j][rr] + cadd) * kLog2e;
        }
    }
    __syncthreads();

    // ---- NEW: merge k-half planes once (psH[0] += psH[1]) -> epilogue reads halve.
    // 1024 float4 chunks (64 rows x 16 quads), 2 per thread; consecutive tid ->
    // consecutive addresses -> 2-way bank aliasing (free).
#pragma unroll
    for (int s = 0; s < 2; ++s) {
        const int id = tid + (s << 9);                 // 0..1023
        const int row = id >> 4, q = id & 15;
        float4* d = (float4*)&smem.psH[0][row][q << 2];
        const float4* a = (const float4*)&smem.psH[1][row][q << 2];
        const float4 va = *a, vd = *d;
        *d = make_float4(vd.x + va.x, vd.y + va.y, vd.z + va.z, vd.w + va.w);
    }
    __syncthreads();

    // ---- epilogue phase 2: packed-f32 softplus; wave owns rows [wave*8,+8), lane=class
    const int q0 = (n0 >> 2);
    f32x2 relu2[8], prod2[8];
#pragma unroll
    for (int rr = 0; rr < 8; ++rr) { relu2[rr] = (f32x2)(0.f); prod2[rr] = (f32x2)(1.f); }

    const f32x2 zero2 = (f32x2)(0.f);
    for (int jc = 0; jc < 64; jc += 8) {
        const float4 ua = ((const float4*)Utp)[(q0 + (jc >> 2) + 0) * kCLS + lane];
        const float4 ub = ((const float4*)Utp)[(q0 + (jc >> 2) + 1) * kCLS + lane];
        const f32x2 u01 = {ua.x, ua.y}, u23 = {ua.z, ua.w};
        const f32x2 u45 = {ub.x, ub.y}, u67 = {ub.z, ub.w};
#pragma unroll
        for (int rr = 0; rr < 8; ++rr) {
            const int row = wave * 8 + rr;
            const float4 p0 = *(const float4*)&smem.psH[0][row][jc];      // broadcast
            const float4 p1 = *(const float4*)&smem.psH[0][row][jc + 4];  // broadcast
            f32x2 tp[4];
            tp[0] = (f32x2){p0.x, p0.y} + u01;
            tp[1] = (f32x2){p0.z, p0.w} + u23;
            tp[2] = (f32x2){p1.x, p1.y} + u45;
            tp[3] = (f32x2){p1.z, p1.w} + u67;
#pragma unroll
            for (int g = 0; g < 4; ++g) {
                const f32x2 t = tp[g];
                f32x2 e;
                e.x = __builtin_amdgcn_exp2f(-__builtin_fabsf(t.x));
                e.y = __builtin_amdgcn_exp2f(-__builtin_fabsf(t.y));
                prod2[rr] = __builtin_elementwise_fma(prod2[rr], e, prod2[rr]);  // *= (1+e), <=2^32/comp
                relu2[rr] += __builtin_elementwise_max(t, zero2);
            }
        }
    }
#pragma unroll
    for (int rr = 0; rr < 8; ++rr) {
        const float contrib = relu2[rr].x + relu2[rr].y +
                              __builtin_amdgcn_logf(prod2[rr].x * prod2[rr].y);  // log2 domain
        Fpart[((size_t)ncol * kB + m0 + wave * 8 + rr) * kCLS + lane] = contrib;
    }
}

// ---------------- Final: sum 16 partials (double), softmax, argmax, one-hot ------------
__global__ __launch_bounds__(256) void softmax_final(const float* __restrict__ Fpart,
                                                     const float* __restrict__ dvec,
                                                     float* __restrict__ out) {
    const int tid = threadIdx.x;
    const int lane = tid & 63, wave = tid >> 6;
    const int row = blockIdx.x * 4 + wave;
    double s = 0.0;
#pragma unroll
    for (int k = 0; k < kHID / 64; ++k)
        s += (double)Fpart[((size_t)k * kB + row) * kCLS + lane];
    const float G = (float)s + dvec[lane] * kLog2e;  // log2-domain logit

    float m = G;
    int mi = lane;
#pragma unroll
    for (int off = 32; off; off >>= 1) {
        const float om = __shfl_xor(m, off);
        const int   oi = __shfl_xor(mi, off);
        if (om > m || (om == m && oi < mi)) { m = om; mi = oi; }  // first-index tie-break
    }
    const float e2 = __builtin_amdgcn_exp2f(G - m);
    float ssum = e2;
#pragma unroll
    for (int off = 32; off; off >>= 1) ssum += __shfl_xor(ssum, off);
    out[(size_t)row * kCLS + lane] = e2 / ssum;
    out[(size_t)kB * kCLS + (size_t)row * kCLS + lane] = (lane == mi) ? 1.0f : 0.0f;
}

// ================= Fallback (round-1, known-passing) if ws is too small =================
constexpr int BM = 64, BN = 64, BK = 16;

__global__ __launch_bounds__(256) void gemm_vw(const float* __restrict__ V,
                                               const float* __restrict__ Wm,
                                               const float* __restrict__ cvec,
                                               float* __restrict__ pre) {
    __shared__ float As[BK][BM + 4];
    __shared__ float Bs[BK][BN + 4];
    const int tid = threadIdx.x;
    const int tx = tid & 15, ty = tid >> 4;
    const int m0 = blockIdx.y * BM, n0 = blockIdx.x * BN;
    const int arow = tid >> 2, acol = (tid & 3) << 2;
    const int brow = tid >> 4, bcol = (tid & 15) << 2;
    const float* vptr = V + (size_t)(m0 + arow) * kVIS + acol;
    const float* wptr = Wm + (size_t)brow * kHID + n0 + bcol;
    float acc[4][4] = {};
    for (int k0 = 0; k0 < kVIS; k0 += BK) {
        const float4 a4 = *(const float4*)(vptr + k0);
        const float4 b4 = *(const float4*)(wptr + (size_t)k0 * kHID);
        __syncthreads();
        As[acol + 0][arow] = a4.x; As[acol + 1][arow] = a4.y;
        As[acol + 2][arow] = a4.z; As[acol + 3][arow] = a4.w;
        *(float4*)&Bs[brow][bcol] = b4;
        __syncthreads();
#pragma unroll
        for (int k = 0; k < BK; ++k) {
            const float4 av = *(const float4*)&As[k][ty << 2];
            const float4 bv = *(const float4*)&Bs[k][tx << 2];
            const float a[4] = {av.x, av.y, av.z, av.w};
            const float b[4] = {bv.x, bv.y, bv.z, bv.w};
#pragma unroll
            for (int i = 0; i < 4; ++i)
#pragma unroll
                for (int j = 0; j < 4; ++j) acc[i][j] += a[i] * b[j];
        }
    }
#pragma unroll
    for (int i = 0; i < 4; ++i) {
        const int row = m0 + (ty << 2) + i;
        const int col = n0 + (tx << 2);
        const float4 cv = *(const float4*)(cvec + col);
        float4 o;
        o.x = acc[i][0] + cv.x; o.y = acc[i][1] + cv.y;
        o.z = acc[i][2] + cv.z; o.w = acc[i][3] + cv.w;
        *(float4*)(pre + (size_t)row * kHID + col) = o;
    }
}

__device__ __forceinline__ float softplus_f(float x) {
    return fmaxf(x, 0.f) + __logf(1.f + __expf(-fabsf(x)));
}

__global__ __launch_bounds__(256) void classify(const float* __restrict__ pre,
                                                const float* __restrict__ U,
                                                const float* __restrict__ dvec,
                                                float* __restrict__ out) {
    __shared__ float preS[4][kHID];
    __shared__ float Fs[4][kCLS];
    const int tid = threadIdx.x;
    const int lane = tid & 63, wave = tid >> 6;
    const int b0 = blockIdx.x * 4;
    const float4* src = (const float4*)(pre + (size_t)b0 * kHID);
    float4* dst = (float4*)preS;
    for (int i = tid; i < kHID; i += 256) dst[i] = src[i];
    __syncthreads();
    for (int yi = 0; yi < 16; ++yi) {
        const int y = (wave << 4) + yi;
        const float* Uy = U + (size_t)y * kHID;
        float a0 = 0.f, a1 = 0.f, a2 = 0.f, a3 = 0.f;
#pragma unroll
        for (int it = 0; it < kHID / 64; ++it) {
            const int j = lane + (it << 6);
            const float u = Uy[j];
            a0 += softplus_f(preS[0][j] + u);
            a1 += softplus_f(preS[1][j] + u);
            a2 += softplus_f(preS[2][j] + u);
            a3 += softplus_f(preS[3][j] + u);
        }
        double d0 = a0, d1 = a1, d2 = a2, d3 = a3;
#pragma unroll
        for (int off = 32; off; off >>= 1) {
            d0 += __shfl_xor(d0, off); d1 += __shfl_xor(d1, off);
            d2 += __shfl_xor(d2, off); d3 += __shfl_xor(d3, off);
        }
        if (lane == 0) {
            const float dy = dvec[y];
            Fs[0][y] = (float)d0 + dy; Fs[1][y] = (float)d1 + dy;
            Fs[2][y] = (float)d2 + dy; Fs[3][y] = (float)d3 + dy;
        }
    }
    __syncthreads();
    const float F = Fs[wave][lane];
    float m = F; int mi = lane;
#pragma unroll
    for (int off = 32; off; off >>= 1) {
        const float om = __shfl_xor(m, off);
        const int oi = __shfl_xor(mi, off);
        if (om > m || (om == m && oi < mi)) { m = om; mi = oi; }
    }
    const float e = __expf(F - m);
    float s = e;
#pragma unroll
    for (int off = 32; off; off >>= 1) s += __shfl_xor(s, off);
    const int row = b0 + wave;
    out[(size_t)row * kCLS + lane] = e / s;
    out[(size_t)kB * kCLS + (size_t)row * kCLS + lane] = (lane == mi) ? 1.0f : 0.0f;
}

extern "C" void kernel_launch(void* const* d_in, const int* in_sizes, int n_in,
                              void* d_out, int out_size, void* d_ws, size_t ws_size,
                              hipStream_t stream) {
    const float* v = (const float*)d_in[0];
    const float* W = (const float*)d_in[1];
    const float* c = (const float*)d_in[2];
    const float* d = (const float*)d_in[3];
    const float* U = (const float*)d_in[4];
    float* out = (float*)d_out;
    char* ws = (char*)d_ws;

    // ws layout: vh 8MB | vl 8MB | Wt_h 4MB | Wt_l 4MB | Utp 256KB | Fpart 8MB
    const size_t need = 33816576;
    if (ws_size >= need) {
        unsigned short* vh  = (unsigned short*)(ws);
        unsigned short* vl  = (unsigned short*)(ws + 8388608);
        unsigned short* wth = (unsigned short*)(ws + 16777216);
        unsigned short* wtl = (unsigned short*)(ws + 20971520);
        float* Utp   = (float*)(ws + 25165824);
        float* Fpart = (float*)(ws + 25427968);
        prep_all<<<6400, 256, 0, stream>>>(v, W, U, vh, vl, wth, wtl, Utp);
        gemm_fused<<<512, 512, 0, stream>>>(vh, vl, wth, wtl, c, Utp, Fpart);
        softmax_final<<<kB / 4, 256, 0, stream>>>(Fpart, d, out);
    } else {
        float* pre = (float*)ws;
        gemm_vw<<<dim3(kHID / BN, kB / BM), 256, 0, stream>>>(v, W, c, pre);
        classify<<<kB / 4, 256, 0, stream>>>(pre, U, d, out);
    }
}